// Round 5
// baseline (281.802 us; speedup 1.0000x reference)
//
#include <hip/hip_runtime.h>
#include <hip/hip_bf16.h>

// GCN layer: out[b,n,o] = dis[b,n] * sum_m adj[b,n,m] * dis[b,m] * (x[b,m,:]@W[o,:] + bias[o])
//
// R5: split-K=2 in k_main. R4's k_main (44us) was barrier/staging-stall-bound:
// issue-rate cap is ~65% MfmaUtil but measured ~17%; per-window prefetch slack
// (~275cyc) < L2/L3 staging latency, and only 2 blocks/CU to overlap the
// vmcnt(0) barrier drains. Split-K=2 -> grid 1024 -> 4 blocks/CU (4 independent
// barrier domains/CU), keeping the 64x128 tile's A-traffic (134MB) and
// 8-MFMA-per-3-stage ratio. Epilogue: atomicAdd (2 adds/elem, same-XCD pair),
// out zero-filled by a tiny kernel first.

#define BATCH 8
#define NN    2048
#define DIN   256
#define DOUT  256
#define RTOT  (BATCH * NN)   // 16384
#define AP    (NN + 32)      // 2080  padded abf row stride (elems)
#define HP    (RTOT + 32)    // 16416 padded hT row stride (elems)

typedef short  bf16x8  __attribute__((ext_vector_type(8)));
typedef short  short4v __attribute__((ext_vector_type(4)));
typedef float  f32x4   __attribute__((ext_vector_type(4)));

__device__ __forceinline__ short f2bf(float f) {
    union { float f; unsigned u; } v; v.f = f;
    unsigned r = v.u + 0x7fffu + ((v.u >> 16) & 1u);   // RNE
    return (short)(r >> 16);
}

__device__ __forceinline__ void gl_lds16(const unsigned short* g, unsigned short* l) {
    __builtin_amdgcn_global_load_lds(
        (const __attribute__((address_space(1))) unsigned int*)g,
        (__attribute__((address_space(3))) unsigned int*)l, 16, 0, 0);
}

// ---------------- K0: zero out ----------------
__global__ __launch_bounds__(256) void k_zero(float4* __restrict__ p) {
    const int i = blockIdx.x * 256 + threadIdx.x;
#pragma unroll
    for (int t = 0; t < 2; t++)
        p[i + t * 2048 * 256] = (float4){0.f, 0.f, 0.f, 0.f};
}

// ---------------- K1: degrees -> dis, and adj -> bf16 (padded rows) ----------------
__global__ __launch_bounds__(256) void k_degree_cvt(const float* __restrict__ adj,
                                                    float* __restrict__ dis,
                                                    unsigned short* __restrict__ abf) {
    const int row = blockIdx.x;                 // 0..16383
    const int n = row & (NN - 1);
    const int tid = threadIdx.x;
    const float4* rp4 = (const float4*)(adj + (size_t)row * NN);
    unsigned short* op = abf + (size_t)row * AP;

    float s = 0.f;
#pragma unroll
    for (int i = 0; i < 2; i++) {
        float4 v = rp4[tid + i * 256];
        s += (v.x + v.y) + (v.z + v.w);
        short4v sv = { f2bf(v.x), f2bf(v.y), f2bf(v.z), f2bf(v.w) };
        *(short4v*)(op + 4 * (tid + i * 256)) = sv;
    }
#pragma unroll
    for (int off = 32; off; off >>= 1) s += __shfl_down(s, off);
    __shared__ float red[4];
    if ((tid & 63) == 0) red[tid >> 6] = s;
    __syncthreads();
    if (tid == 0) {
        float tot  = (red[0] + red[1]) + (red[2] + red[3]);
        float diag = ((const float*)rp4)[n];
        dis[row]   = rsqrtf(tot - diag);
    }
}

// ---------------- K2: projection, transposed + dis-folded, padded hT ----------------
__global__ __launch_bounds__(256) void k_proj(const float* __restrict__ x,
                                              const float* __restrict__ W,
                                              const float* __restrict__ bias,
                                              const float* __restrict__ dis,
                                              unsigned short* __restrict__ hT) {
    const int mt  = blockIdx.y;           // 0..1   (o-tile of 128)
    const int nt  = blockIdx.x;           // 0..127 (r-tile of 128)
    const int tid = threadIdx.x;
    const int w = tid >> 6, lane = tid & 63;
    const int wr = w >> 1, wc = w & 1;
    const int l16 = lane & 15, quad = lane >> 4;

    __shared__ short As[128][32];
    __shared__ short Bs[128][32];

    f32x4 acc[4][4];
#pragma unroll
    for (int i = 0; i < 4; i++)
#pragma unroll
        for (int j = 0; j < 4; j++) acc[i][j] = (f32x4){0.f, 0.f, 0.f, 0.f};

    const float4* Wf4 = (const float4*)(W + (size_t)mt * 128 * DIN);
    const float4* Xf4 = (const float4*)(x + (size_t)nt * 128 * DIN);

    for (int kk = 0; kk < DIN / 32; kk++) {
        const int k0 = kk * 32;
        __syncthreads();
#pragma unroll
        for (int it = 0; it < 4; it++) {
            int idx = tid + it * 256;
            int r = idx >> 3, c = idx & 7;
            float4 va = Wf4[(size_t)r * (DIN / 4) + (k0 >> 2) + c];
            float4 vb = Xf4[(size_t)r * (DIN / 4) + (k0 >> 2) + c];
            short4v sa = { f2bf(va.x), f2bf(va.y), f2bf(va.z), f2bf(va.w) };
            short4v sb = { f2bf(vb.x), f2bf(vb.y), f2bf(vb.z), f2bf(vb.w) };
            *(short4v*)&As[r][c * 4] = sa;
            *(short4v*)&Bs[r][c * 4] = sb;
        }
        __syncthreads();
        bf16x8 af[4], bfv[4];
#pragma unroll
        for (int i = 0; i < 4; i++) af[i]  = *(bf16x8*)&As[wr * 64 + i * 16 + l16][quad * 8];
#pragma unroll
        for (int j = 0; j < 4; j++) bfv[j] = *(bf16x8*)&Bs[wc * 64 + j * 16 + l16][quad * 8];
#pragma unroll
        for (int i = 0; i < 4; i++)
#pragma unroll
            for (int j = 0; j < 4; j++)
                acc[i][j] = __builtin_amdgcn_mfma_f32_16x16x32_bf16(af[i], bfv[j], acc[i][j], 0, 0, 0);
    }

#pragma unroll
    for (int i = 0; i < 4; i++) {
        const int orow_base = mt * 128 + wr * 64 + i * 16 + quad * 4;
#pragma unroll
        for (int r = 0; r < 4; r++) {
            const int orow = orow_base + r;
            const float bb = bias[orow];
#pragma unroll
            for (int j = 0; j < 4; j++) {
                const int col = nt * 128 + wc * 64 + j * 16 + l16;
                float v = (acc[i][j][r] + bb) * dis[col];
                hT[(size_t)orow * HP + col] = (unsigned short)f2bf(v);
            }
        }
    }
}

// ---------------- K3: out += dis[n] * (abf @ hT), LDS-staged, split-K=2 ----------------
// Per batch: M=2048(n), N=256(o), K=2048 split into 2x1024. Block tile 64x128, BK=32.
// Grid 1024 = 4 blocks/CU: bx&7=batch (XCD L2 affinity), (bx>>3)&31=mtile,
// (bx>>8)&1=ctile, bx>>9=khalf. Both khalves of a tile share bx&7 -> same-XCD atomics.
__global__ __launch_bounds__(256, 4) void k_main(const unsigned short* __restrict__ abf,
                                                 const unsigned short* __restrict__ hT,
                                                 const float* __restrict__ dis,
                                                 float* __restrict__ out) {
    const int bx    = blockIdx.x;
    const int b     = bx & 7;
    const int mtile = (bx >> 3) & 31;
    const int ctile = (bx >> 8) & 1;
    const int khalf = bx >> 9;            // 0..1
    const int n0    = mtile * 64;
    const int k0g   = khalf * (NN / 2);   // 0 or 1024
    const int tid  = threadIdx.x;
    const int w    = tid >> 6, lane = tid & 63;
    const int l16  = lane & 15, quad = lane >> 4;
    const int lr   = lane >> 2;           // 0..15 (staging row-within-group)
    const int lc   = (lane & 3) * 8;      // 0,8,16,24 (staging elem offset)

    __shared__ short As[2][64][32];       // adj rows(n) x k, bf16; 64B rows
    __shared__ short Bs[2][128][32];      // hT rows(o) x k, bf16

    const unsigned short* agp  = abf + (size_t)(b * NN + n0 + w * 16 + lr) * AP + k0g + lc;
    const unsigned short* bgp0 = hT + (size_t)(ctile * 128 + w * 32 + lr) * HP + b * NN + k0g + lc;
    const unsigned short* bgp1 = bgp0 + (size_t)16 * HP;
    unsigned short* alp[2]  = { (unsigned short*)&As[0][w * 16][0], (unsigned short*)&As[1][w * 16][0] };
    unsigned short* blp0[2] = { (unsigned short*)&Bs[0][w * 32][0], (unsigned short*)&Bs[1][w * 32][0] };
    unsigned short* blp1[2] = { (unsigned short*)&Bs[0][w * 32 + 16][0], (unsigned short*)&Bs[1][w * 32 + 16][0] };

    f32x4 acc[4][2];
#pragma unroll
    for (int i = 0; i < 4; i++)
#pragma unroll
        for (int j = 0; j < 2; j++) acc[i][j] = (f32x4){0.f, 0.f, 0.f, 0.f};

    gl_lds16(agp, alp[0]);
    gl_lds16(bgp0, blp0[0]);
    gl_lds16(bgp1, blp1[0]);

    const int NW = NN / 2 / 32;   // 32 windows
    for (int kk = 0; kk < NW; kk++) {
        const int cur = kk & 1, nxt = cur ^ 1;
        __syncthreads();
        if (kk < NW - 1) {
            const int ko = (kk + 1) * 32;
            gl_lds16(agp + ko, alp[nxt]);
            gl_lds16(bgp0 + ko, blp0[nxt]);
            gl_lds16(bgp1 + ko, blp1[nxt]);
        }
        bf16x8 af[4], bfv[2];
#pragma unroll
        for (int i = 0; i < 4; i++) af[i]  = *(bf16x8*)&As[cur][i * 16 + l16][quad * 8];
#pragma unroll
        for (int j = 0; j < 2; j++) bfv[j] = *(bf16x8*)&Bs[cur][w * 32 + j * 16 + l16][quad * 8];
#pragma unroll
        for (int i = 0; i < 4; i++)
#pragma unroll
            for (int j = 0; j < 2; j++)
                acc[i][j] = __builtin_amdgcn_mfma_f32_16x16x32_bf16(af[i], bfv[j], acc[i][j], 0, 0, 0);
    }

    const float* disb = dis + (size_t)b * NN;
#pragma unroll
    for (int i = 0; i < 4; i++) {
#pragma unroll
        for (int r = 0; r < 4; r++) {
            const int nrow = n0 + i * 16 + quad * 4 + r;
            const float dn = disb[nrow];
#pragma unroll
            for (int j = 0; j < 2; j++) {
                const int ocol = ctile * 128 + w * 32 + j * 16 + l16;
                atomicAdd(&out[((size_t)b * NN + nrow) * DOUT + ocol], dn * acc[i][j][r]);
            }
        }
    }
}

extern "C" void kernel_launch(void* const* d_in, const int* in_sizes, int n_in,
                              void* d_out, int out_size, void* d_ws, size_t ws_size,
                              hipStream_t stream) {
    const float* x    = (const float*)d_in[0];
    const float* adj  = (const float*)d_in[1];
    const float* W    = (const float*)d_in[2];
    const float* bias = (const float*)d_in[3];
    float* out = (float*)d_out;

    float* dis = (float*)d_ws;                                             // 64 KB
    unsigned short* hT  = (unsigned short*)((char*)d_ws + 65536);          // 256*16416*2 = 8.4 MB
    unsigned short* abf = (unsigned short*)((char*)d_ws + 65536 + (size_t)DOUT * HP * 2); // 68 MB

    k_zero<<<2048, 256, 0, stream>>>((float4*)out);   // 4.19M floats = 2048*256*2 float4
    k_degree_cvt<<<RTOT, 256, 0, stream>>>(adj, dis, abf);
    k_proj<<<dim3(128, 2), 256, 0, stream>>>(x, W, bias, dis, hT);
    k_main<<<1024, 256, 0, stream>>>(abf, hT, dis, out);
}

// Round 6
// 270.046 us; speedup vs baseline: 1.0435x; 1.0435x over previous
//
#include <hip/hip_runtime.h>
#include <hip/hip_bf16.h>

// GCN layer: out[b,n,o] = dis[b,n] * sum_m adj[b,n,m] * dis[b,m] * (x[b,m,:]@W[o,:] + bias[o])
//
// R6: k_main K-loop restructured AITER-style. R4/R5 showed the 2-barrier
// __syncthreads K-loop pays ~full L3 staging latency per window (compiler's
// vmcnt(0) drain before s_barrier caps prefetch depth at 1). Now: 4 LDS slots,
// prefetch distance 3, raw s_barrier + manual s_waitcnt vmcnt(6/3/0) (never 0
// in steady state) -> 3 windows of global_load_lds in flight while MFMAs run.
// Slot overwrite (k+3 into (k+3)&3) is safe with ONE barrier: that slot was
// last read at window k-1, and each wave's k-1 ds_reads are lgkm-waited before
// its k-1 MFMAs, which precede barrier k.
// Split-K / atomics / k_zero reverted (R5 regression: atomic RMW cost > barrier
// domain gain).

#define BATCH 8
#define NN    2048
#define DIN   256
#define DOUT  256
#define RTOT  (BATCH * NN)   // 16384
#define AP    (NN + 32)      // 2080  padded abf row stride (elems)
#define HP    (RTOT + 32)    // 16416 padded hT row stride (elems)

typedef short  bf16x8  __attribute__((ext_vector_type(8)));
typedef short  short4v __attribute__((ext_vector_type(4)));
typedef float  f32x4   __attribute__((ext_vector_type(4)));

__device__ __forceinline__ short f2bf(float f) {
    union { float f; unsigned u; } v; v.f = f;
    unsigned r = v.u + 0x7fffu + ((v.u >> 16) & 1u);   // RNE
    return (short)(r >> 16);
}

__device__ __forceinline__ void gl_lds16(const unsigned short* g, unsigned short* l) {
    __builtin_amdgcn_global_load_lds(
        (const __attribute__((address_space(1))) unsigned int*)g,
        (__attribute__((address_space(3))) unsigned int*)l, 16, 0, 0);
}

// ---------------- K1: degrees -> dis, and adj -> bf16 (padded rows) ----------------
__global__ __launch_bounds__(256) void k_degree_cvt(const float* __restrict__ adj,
                                                    float* __restrict__ dis,
                                                    unsigned short* __restrict__ abf) {
    const int row = blockIdx.x;                 // 0..16383
    const int n = row & (NN - 1);
    const int tid = threadIdx.x;
    const float4* rp4 = (const float4*)(adj + (size_t)row * NN);
    unsigned short* op = abf + (size_t)row * AP;

    float s = 0.f;
#pragma unroll
    for (int i = 0; i < 2; i++) {
        float4 v = rp4[tid + i * 256];
        s += (v.x + v.y) + (v.z + v.w);
        short4v sv = { f2bf(v.x), f2bf(v.y), f2bf(v.z), f2bf(v.w) };
        *(short4v*)(op + 4 * (tid + i * 256)) = sv;
    }
#pragma unroll
    for (int off = 32; off; off >>= 1) s += __shfl_down(s, off);
    __shared__ float red[4];
    if ((tid & 63) == 0) red[tid >> 6] = s;
    __syncthreads();
    if (tid == 0) {
        float tot  = (red[0] + red[1]) + (red[2] + red[3]);
        float diag = ((const float*)rp4)[n];
        dis[row]   = rsqrtf(tot - diag);
    }
}

// ---------------- K2: projection, transposed + dis-folded, padded hT ----------------
__global__ __launch_bounds__(256) void k_proj(const float* __restrict__ x,
                                              const float* __restrict__ W,
                                              const float* __restrict__ bias,
                                              const float* __restrict__ dis,
                                              unsigned short* __restrict__ hT) {
    const int mt  = blockIdx.y;           // 0..1   (o-tile of 128)
    const int nt  = blockIdx.x;           // 0..127 (r-tile of 128)
    const int tid = threadIdx.x;
    const int w = tid >> 6, lane = tid & 63;
    const int wr = w >> 1, wc = w & 1;
    const int l16 = lane & 15, quad = lane >> 4;

    __shared__ short As[128][32];
    __shared__ short Bs[128][32];

    f32x4 acc[4][4];
#pragma unroll
    for (int i = 0; i < 4; i++)
#pragma unroll
        for (int j = 0; j < 4; j++) acc[i][j] = (f32x4){0.f, 0.f, 0.f, 0.f};

    const float4* Wf4 = (const float4*)(W + (size_t)mt * 128 * DIN);
    const float4* Xf4 = (const float4*)(x + (size_t)nt * 128 * DIN);

    for (int kk = 0; kk < DIN / 32; kk++) {
        const int k0 = kk * 32;
        __syncthreads();
#pragma unroll
        for (int it = 0; it < 4; it++) {
            int idx = tid + it * 256;
            int r = idx >> 3, c = idx & 7;
            float4 va = Wf4[(size_t)r * (DIN / 4) + (k0 >> 2) + c];
            float4 vb = Xf4[(size_t)r * (DIN / 4) + (k0 >> 2) + c];
            short4v sa = { f2bf(va.x), f2bf(va.y), f2bf(va.z), f2bf(va.w) };
            short4v sb = { f2bf(vb.x), f2bf(vb.y), f2bf(vb.z), f2bf(vb.w) };
            *(short4v*)&As[r][c * 4] = sa;
            *(short4v*)&Bs[r][c * 4] = sb;
        }
        __syncthreads();
        bf16x8 af[4], bfv[4];
#pragma unroll
        for (int i = 0; i < 4; i++) af[i]  = *(bf16x8*)&As[wr * 64 + i * 16 + l16][quad * 8];
#pragma unroll
        for (int j = 0; j < 4; j++) bfv[j] = *(bf16x8*)&Bs[wc * 64 + j * 16 + l16][quad * 8];
#pragma unroll
        for (int i = 0; i < 4; i++)
#pragma unroll
            for (int j = 0; j < 4; j++)
                acc[i][j] = __builtin_amdgcn_mfma_f32_16x16x32_bf16(af[i], bfv[j], acc[i][j], 0, 0, 0);
    }

#pragma unroll
    for (int i = 0; i < 4; i++) {
        const int orow_base = mt * 128 + wr * 64 + i * 16 + quad * 4;
#pragma unroll
        for (int r = 0; r < 4; r++) {
            const int orow = orow_base + r;
            const float bb = bias[orow];
#pragma unroll
            for (int j = 0; j < 4; j++) {
                const int col = nt * 128 + wc * 64 + j * 16 + l16;
                float v = (acc[i][j][r] + bb) * dis[col];
                hT[(size_t)orow * HP + col] = (unsigned short)f2bf(v);
            }
        }
    }
}

// ---------------- K3: out = dis[n] * (abf @ hT), 4-slot async pipeline ----------------
// Per batch: M=2048(n), K=2048(m), N=256(o). Block tile 64x128, BK=32, 64 windows.
// Grid 512: bx&7=batch (XCD L2 affinity for hT), (bx>>3)&31=mtile, bx>>8=ctile.
__global__ __launch_bounds__(256, 2) void k_main(const unsigned short* __restrict__ abf,
                                                 const unsigned short* __restrict__ hT,
                                                 const float* __restrict__ dis,
                                                 float* __restrict__ out) {
    const int bx    = blockIdx.x;
    const int b     = bx & 7;
    const int mtile = (bx >> 3) & 31;
    const int ctile = bx >> 8;            // 0..1
    const int n0    = mtile * 64;
    const int tid  = threadIdx.x;
    const int w    = tid >> 6, lane = tid & 63;
    const int l16  = lane & 15, quad = lane >> 4;
    const int lr   = lane >> 2;           // 0..15 (staging row-within-group)
    const int lc   = (lane & 3) * 8;      // 0,8,16,24 (staging elem offset)

    __shared__ short As[4][64][32];       // 16 KB: adj rows(n) x k
    __shared__ short Bs[4][128][32];      // 32 KB: hT rows(o) x k

    const unsigned short* agp  = abf + (size_t)(b * NN + n0 + w * 16 + lr) * AP + lc;
    const unsigned short* bgp0 = hT + (size_t)(ctile * 128 + w * 32 + lr) * HP + b * NN + lc;
    const unsigned short* bgp1 = bgp0 + (size_t)16 * HP;

    f32x4 acc[4][2];
#pragma unroll
    for (int i = 0; i < 4; i++)
#pragma unroll
        for (int j = 0; j < 2; j++) acc[i][j] = (f32x4){0.f, 0.f, 0.f, 0.f};

#define STAGE(slot, kw) do {                                            \
        const int _ko = (kw) * 32;                                      \
        gl_lds16(agp + _ko,  (unsigned short*)&As[slot][w * 16][0]);    \
        gl_lds16(bgp0 + _ko, (unsigned short*)&Bs[slot][w * 32][0]);    \
        gl_lds16(bgp1 + _ko, (unsigned short*)&Bs[slot][w * 32 + 16][0]); \
    } while (0)

#define CONSUME(slot) do {                                              \
        bf16x8 af[4], bfv[2];                                           \
        _Pragma("unroll")                                               \
        for (int _i = 0; _i < 4; _i++)                                  \
            af[_i]  = *(bf16x8*)&As[slot][_i * 16 + l16][quad * 8];     \
        _Pragma("unroll")                                               \
        for (int _j = 0; _j < 2; _j++)                                  \
            bfv[_j] = *(bf16x8*)&Bs[slot][w * 32 + _j * 16 + l16][quad * 8]; \
        _Pragma("unroll")                                               \
        for (int _i = 0; _i < 4; _i++)                                  \
            _Pragma("unroll")                                           \
            for (int _j = 0; _j < 2; _j++)                              \
                acc[_i][_j] = __builtin_amdgcn_mfma_f32_16x16x32_bf16(  \
                    af[_i], bfv[_j], acc[_i][_j], 0, 0, 0);             \
    } while (0)

    // Prologue: stage windows 0..2 into slots 0..2 (9 vmem ops in flight).
    STAGE(0, 0);
    STAGE(1, 1);
    STAGE(2, 2);

    // Steady state: wait oldest window (keep 2 in flight), raw barrier, refill, consume.
    for (int k = 0; k < 62; k++) {
        asm volatile("s_waitcnt vmcnt(6)" ::: "memory");
        asm volatile("s_barrier" ::: "memory");
        if (k < 61) STAGE((k + 3) & 3, k + 3);
        const int s = k & 3;
        CONSUME(s);
    }
    asm volatile("s_waitcnt vmcnt(3)" ::: "memory");
    asm volatile("s_barrier" ::: "memory");
    CONSUME(2);   // k = 62
    asm volatile("s_waitcnt vmcnt(0)" ::: "memory");
    asm volatile("s_barrier" ::: "memory");
    CONSUME(3);   // k = 63

#undef STAGE
#undef CONSUME

    const float* disb = dis + (size_t)b * NN;
#pragma unroll
    for (int i = 0; i < 4; i++) {
#pragma unroll
        for (int r = 0; r < 4; r++) {
            const int nrow = n0 + i * 16 + quad * 4 + r;
            const float dn = disb[nrow];
#pragma unroll
            for (int j = 0; j < 2; j++) {
                const int ocol = ctile * 128 + w * 32 + j * 16 + l16;
                out[((size_t)b * NN + nrow) * DOUT + ocol] = dn * acc[i][j][r];
            }
        }
    }
}

extern "C" void kernel_launch(void* const* d_in, const int* in_sizes, int n_in,
                              void* d_out, int out_size, void* d_ws, size_t ws_size,
                              hipStream_t stream) {
    const float* x    = (const float*)d_in[0];
    const float* adj  = (const float*)d_in[1];
    const float* W    = (const float*)d_in[2];
    const float* bias = (const float*)d_in[3];
    float* out = (float*)d_out;

    float* dis = (float*)d_ws;                                             // 64 KB
    unsigned short* hT  = (unsigned short*)((char*)d_ws + 65536);          // 256*16416*2 = 8.4 MB
    unsigned short* abf = (unsigned short*)((char*)d_ws + 65536 + (size_t)DOUT * HP * 2); // 68 MB

    k_degree_cvt<<<RTOT, 256, 0, stream>>>(adj, dis, abf);
    k_proj<<<dim3(128, 2), 256, 0, stream>>>(x, W, bias, dis, hT);
    k_main<<<512, 256, 0, stream>>>(abf, hT, dis, out);
}

// Round 7
// 259.069 us; speedup vs baseline: 1.0877x; 1.0424x over previous
//
#include <hip/hip_runtime.h>
#include <hip/hip_bf16.h>

// GCN layer: out[b,n,o] = dis[b,n] * sum_m adj[b,n,m] * dis[b,m] * (x[b,m,:]@W[o,:] + bias[o])
//
// R7: k_main = BK=128 barrier-amortized K-loop. R6's manual vmcnt pipeline
// regressed (compiler re-inserts vmcnt(0) for the global_load_lds->ds_read dep;
// m135/m139 confirmed dead end). Instead amortize the one unavoidable drain:
// single 48KB buffer = 4 contiguous R4-style sub-windows (As[4][64][32],
// Bs[4][128][32]); per group: stage 12x gl_lds16, ONE __syncthreads (one
// ~800cyc drain), consume 32 MFMA + 24 ds_read per wave (~1240cyc/SIMD at
// 2 waves/SIMD), one cheap lgkm-only barrier, x16 groups. Drain:work goes
// 800:155 -> 800:1240; the 2nd co-resident block fills the drain.

#define BATCH 8
#define NN    2048
#define DIN   256
#define DOUT  256
#define RTOT  (BATCH * NN)   // 16384
#define AP    (NN + 32)      // 2080  padded abf row stride (elems)
#define HP    (RTOT + 32)    // 16416 padded hT row stride (elems)

typedef short  bf16x8  __attribute__((ext_vector_type(8)));
typedef short  short4v __attribute__((ext_vector_type(4)));
typedef float  f32x4   __attribute__((ext_vector_type(4)));

__device__ __forceinline__ short f2bf(float f) {
    union { float f; unsigned u; } v; v.f = f;
    unsigned r = v.u + 0x7fffu + ((v.u >> 16) & 1u);   // RNE
    return (short)(r >> 16);
}

__device__ __forceinline__ void gl_lds16(const unsigned short* g, unsigned short* l) {
    __builtin_amdgcn_global_load_lds(
        (const __attribute__((address_space(1))) unsigned int*)g,
        (__attribute__((address_space(3))) unsigned int*)l, 16, 0, 0);
}

// ---------------- K1: degrees -> dis, and adj -> bf16 (padded rows) ----------------
__global__ __launch_bounds__(256) void k_degree_cvt(const float* __restrict__ adj,
                                                    float* __restrict__ dis,
                                                    unsigned short* __restrict__ abf) {
    const int row = blockIdx.x;                 // 0..16383
    const int n = row & (NN - 1);
    const int tid = threadIdx.x;
    const float4* rp4 = (const float4*)(adj + (size_t)row * NN);
    unsigned short* op = abf + (size_t)row * AP;

    float s = 0.f;
#pragma unroll
    for (int i = 0; i < 2; i++) {
        float4 v = rp4[tid + i * 256];
        s += (v.x + v.y) + (v.z + v.w);
        short4v sv = { f2bf(v.x), f2bf(v.y), f2bf(v.z), f2bf(v.w) };
        *(short4v*)(op + 4 * (tid + i * 256)) = sv;
    }
#pragma unroll
    for (int off = 32; off; off >>= 1) s += __shfl_down(s, off);
    __shared__ float red[4];
    if ((tid & 63) == 0) red[tid >> 6] = s;
    __syncthreads();
    if (tid == 0) {
        float tot  = (red[0] + red[1]) + (red[2] + red[3]);
        float diag = ((const float*)rp4)[n];
        dis[row]   = rsqrtf(tot - diag);
    }
}

// ---------------- K2: projection, transposed + dis-folded, padded hT ----------------
__global__ __launch_bounds__(256) void k_proj(const float* __restrict__ x,
                                              const float* __restrict__ W,
                                              const float* __restrict__ bias,
                                              const float* __restrict__ dis,
                                              unsigned short* __restrict__ hT) {
    const int mt  = blockIdx.y;           // 0..1   (o-tile of 128)
    const int nt  = blockIdx.x;           // 0..127 (r-tile of 128)
    const int tid = threadIdx.x;
    const int w = tid >> 6, lane = tid & 63;
    const int wr = w >> 1, wc = w & 1;
    const int l16 = lane & 15, quad = lane >> 4;

    __shared__ short As[128][32];
    __shared__ short Bs[128][32];

    f32x4 acc[4][4];
#pragma unroll
    for (int i = 0; i < 4; i++)
#pragma unroll
        for (int j = 0; j < 4; j++) acc[i][j] = (f32x4){0.f, 0.f, 0.f, 0.f};

    const float4* Wf4 = (const float4*)(W + (size_t)mt * 128 * DIN);
    const float4* Xf4 = (const float4*)(x + (size_t)nt * 128 * DIN);

    for (int kk = 0; kk < DIN / 32; kk++) {
        const int k0 = kk * 32;
        __syncthreads();
#pragma unroll
        for (int it = 0; it < 4; it++) {
            int idx = tid + it * 256;
            int r = idx >> 3, c = idx & 7;
            float4 va = Wf4[(size_t)r * (DIN / 4) + (k0 >> 2) + c];
            float4 vb = Xf4[(size_t)r * (DIN / 4) + (k0 >> 2) + c];
            short4v sa = { f2bf(va.x), f2bf(va.y), f2bf(va.z), f2bf(va.w) };
            short4v sb = { f2bf(vb.x), f2bf(vb.y), f2bf(vb.z), f2bf(vb.w) };
            *(short4v*)&As[r][c * 4] = sa;
            *(short4v*)&Bs[r][c * 4] = sb;
        }
        __syncthreads();
        bf16x8 af[4], bfv[4];
#pragma unroll
        for (int i = 0; i < 4; i++) af[i]  = *(bf16x8*)&As[wr * 64 + i * 16 + l16][quad * 8];
#pragma unroll
        for (int j = 0; j < 4; j++) bfv[j] = *(bf16x8*)&Bs[wc * 64 + j * 16 + l16][quad * 8];
#pragma unroll
        for (int i = 0; i < 4; i++)
#pragma unroll
            for (int j = 0; j < 4; j++)
                acc[i][j] = __builtin_amdgcn_mfma_f32_16x16x32_bf16(af[i], bfv[j], acc[i][j], 0, 0, 0);
    }

#pragma unroll
    for (int i = 0; i < 4; i++) {
        const int orow_base = mt * 128 + wr * 64 + i * 16 + quad * 4;
#pragma unroll
        for (int r = 0; r < 4; r++) {
            const int orow = orow_base + r;
            const float bb = bias[orow];
#pragma unroll
            for (int j = 0; j < 4; j++) {
                const int col = nt * 128 + wc * 64 + j * 16 + l16;
                float v = (acc[i][j][r] + bb) * dis[col];
                hT[(size_t)orow * HP + col] = (unsigned short)f2bf(v);
            }
        }
    }
}

// ---------------- K3: out = dis[n] * (abf @ hT), BK=128 single-buffer ----------------
// Per batch: M=2048(n), K=2048(m), N=256(o). Block tile 64x128; 16 groups of BK=128
// (4 sub-windows of 32). Grid 512 = 2 blocks/CU: bx&7=batch (XCD L2 affinity for hT),
// (bx>>3)&31=mtile, bx>>8=ctile.
__global__ __launch_bounds__(256, 2) void k_main(const unsigned short* __restrict__ abf,
                                                 const unsigned short* __restrict__ hT,
                                                 const float* __restrict__ dis,
                                                 float* __restrict__ out) {
    const int bx    = blockIdx.x;
    const int b     = bx & 7;
    const int mtile = (bx >> 3) & 31;
    const int ctile = bx >> 8;            // 0..1
    const int n0    = mtile * 64;
    const int tid  = threadIdx.x;
    const int w    = tid >> 6, lane = tid & 63;
    const int l16  = lane & 15, quad = lane >> 4;
    const int lr   = lane >> 2;           // 0..15 (staging row-within-group)
    const int lc   = (lane & 3) * 8;      // 0,8,16,24 (staging elem offset)

    __shared__ short As[4][64][32];       // 16 KB: 4 sub-windows of adj rows(n) x 32k
    __shared__ short Bs[4][128][32];      // 32 KB: 4 sub-windows of hT rows(o) x 32k

    const unsigned short* agp  = abf + (size_t)(b * NN + n0 + w * 16 + lr) * AP + lc;
    const unsigned short* bgp0 = hT + (size_t)(ctile * 128 + w * 32 + lr) * HP + b * NN + lc;
    const unsigned short* bgp1 = bgp0 + (size_t)16 * HP;

    f32x4 acc[4][2];
#pragma unroll
    for (int i = 0; i < 4; i++)
#pragma unroll
        for (int j = 0; j < 2; j++) acc[i][j] = (f32x4){0.f, 0.f, 0.f, 0.f};

    for (int g = 0; g < NN / 128; g++) {          // 16 groups
        // Stage 4 sub-windows (12 gl_lds16 per thread), then ONE drain.
#pragma unroll
        for (int s = 0; s < 4; s++) {
            const int ko = g * 128 + s * 32;
            gl_lds16(agp + ko,  (unsigned short*)&As[s][w * 16][0]);
            gl_lds16(bgp0 + ko, (unsigned short*)&Bs[s][w * 32][0]);
            gl_lds16(bgp1 + ko, (unsigned short*)&Bs[s][w * 32 + 16][0]);
        }
        __syncthreads();   // drain staging once per 128-K of work
        // Consume: 32 MFMA + 24 ds_read_b128 per wave.
#pragma unroll
        for (int s = 0; s < 4; s++) {
            bf16x8 af[4], bfv[2];
#pragma unroll
            for (int i = 0; i < 4; i++) af[i]  = *(bf16x8*)&As[s][i * 16 + l16][quad * 8];
#pragma unroll
            for (int j = 0; j < 2; j++) bfv[j] = *(bf16x8*)&Bs[s][w * 32 + j * 16 + l16][quad * 8];
#pragma unroll
            for (int i = 0; i < 4; i++)
#pragma unroll
                for (int j = 0; j < 2; j++)
                    acc[i][j] = __builtin_amdgcn_mfma_f32_16x16x32_bf16(af[i], bfv[j], acc[i][j], 0, 0, 0);
        }
        __syncthreads();   // all ds_reads retired before restage (lgkm-only; vmem already 0)
    }

    const float* disb = dis + (size_t)b * NN;
#pragma unroll
    for (int i = 0; i < 4; i++) {
#pragma unroll
        for (int r = 0; r < 4; r++) {
            const int nrow = n0 + i * 16 + quad * 4 + r;
            const float dn = disb[nrow];
#pragma unroll
            for (int j = 0; j < 2; j++) {
                const int ocol = ctile * 128 + w * 32 + j * 16 + l16;
                out[((size_t)b * NN + nrow) * DOUT + ocol] = dn * acc[i][j][r];
            }
        }
    }
}

extern "C" void kernel_launch(void* const* d_in, const int* in_sizes, int n_in,
                              void* d_out, int out_size, void* d_ws, size_t ws_size,
                              hipStream_t stream) {
    const float* x    = (const float*)d_in[0];
    const float* adj  = (const float*)d_in[1];
    const float* W    = (const float*)d_in[2];
    const float* bias = (const float*)d_in[3];
    float* out = (float*)d_out;

    float* dis = (float*)d_ws;                                             // 64 KB
    unsigned short* hT  = (unsigned short*)((char*)d_ws + 65536);          // 256*16416*2 = 8.4 MB
    unsigned short* abf = (unsigned short*)((char*)d_ws + 65536 + (size_t)DOUT * HP * 2); // 68 MB

    k_degree_cvt<<<RTOT, 256, 0, stream>>>(adj, dis, abf);
    k_proj<<<dim3(128, 2), 256, 0, stream>>>(x, W, bias, dis, hT);
    k_main<<<512, 256, 0, stream>>>(abf, hT, dis, out);
}